// Round 1
// baseline (100836.389 us; speedup 1.0000x reference)
//
#include <hip/hip_runtime.h>

// ============================================================================
// R1: persistent cooperative kernel, weight-stationary (W in MFMA B-frag regs),
// 4 grid barriers/step, fp16 MFMA 16x16x32, fp32 state. Deferred output GEMM
// epilogue. Label: "R1 coop 4-barrier f16 MFMA"
// ============================================================================

#define DI __device__ __forceinline__

typedef _Float16 f16;
typedef _Float16 f16x8 __attribute__((ext_vector_type(8)));
typedef float f32x4 __attribute__((ext_vector_type(4)));

constexpr int Bn = 64, Tn = 800, Un = 96, CD = 64, Hn = 400;
// A/W layouts (k-order), zero-padded so every 32-wide k-step is valid:
//  A1/W1: [w 64 | h1 400 | x 3 | 0.. ]  padK=512, pitch P1=520, 16 ksteps
//  A2/W2: [w 64 | h1 400 | x 3 | 0(13) | h2rec 400 | 0(16)] padK=896, P2=904, 28 ks
//  A3/W3: [w 64 | h2 400 | x 3 | 0(13) | h3rec 400 | 0(16)] same shape
//  Am/Wm: [h1 400 | h2 400 | h3 400 | 0(80)] padK=1280, PM=1288, 40 ks
constexpr int P1 = 520, KPW1 = 4;    // 16 ksteps / 4 waves
constexpr int P2 = 904, KPW2 = 7;    // 28 ksteps / 4 waves
constexpr int PM = 1288, KPWM = 10;  // 40 ksteps / 4 waves
constexpr int NWG = 230, NGRP = 16;

// ---- workspace layout (bytes) ----
constexpr size_t OFF_W1 = 0;
constexpr size_t SZ_W1 = (size_t)1600 * P1 * 2;
constexpr size_t OFF_W2 = OFF_W1 + SZ_W1;
constexpr size_t SZ_W2 = (size_t)1600 * P2 * 2;
constexpr size_t OFF_W3 = OFF_W2 + SZ_W2;
constexpr size_t OFF_WM = OFF_W3 + SZ_W2;
constexpr size_t SZ_WM = (size_t)128 * PM * 2;
constexpr size_t OFF_A1 = OFF_WM + SZ_WM;
constexpr size_t SZ_A1 = (size_t)2 * 64 * P1 * 2;
constexpr size_t OFF_A2 = OFF_A1 + SZ_A1;
constexpr size_t SZ_A2 = (size_t)2 * 64 * P2 * 2;
constexpr size_t OFF_A3 = OFF_A2 + SZ_A2;
constexpr size_t OFF_AM = OFF_A3 + SZ_A2;
constexpr size_t SZ_AM = (size_t)2 * 64 * PM * 2;
constexpr size_t OFF_TEB = OFF_AM + SZ_AM;
constexpr size_t SZ_TEB = (size_t)64 * 96 * 64 * 2;
constexpr size_t OFF_BS1 = OFF_TEB + SZ_TEB;
constexpr size_t OFF_BS2 = OFF_BS1 + 6400;
constexpr size_t OFF_BS3 = OFF_BS2 + 6400;
constexpr size_t OFF_BW = OFF_BS3 + 6400;
constexpr size_t OFF_BM = OFF_BW + 128;
constexpr size_t OFF_BAR = OFF_BM + 512;
constexpr size_t SZ_BAR = 8192;
constexpr size_t OFF_RES = OFF_BAR + SZ_BAR;
constexpr size_t SZ_RES = (size_t)800 * 64 * 128 * 4;

// output offsets (fp32 elements), tuple order: eos,pi,mux,muy,sx,sy,rho
constexpr size_t O_EOS = 0;
constexpr size_t O_PI = 51200;
constexpr size_t O_MUX = 1075200;
constexpr size_t O_MUY = 2099200;
constexpr size_t O_SX = 3123200;
constexpr size_t O_SY = 4147200;
constexpr size_t O_RHO = 5171200;

// ---- two-level grid barrier (sense via monotonically increasing gen) ----
DI void gridbar(unsigned* barr) {
  __threadfence();
  __syncthreads();
  if (threadIdx.x == 0) {
    const int g = (int)(blockIdx.x & (NGRP - 1));
    const unsigned gsz = (unsigned)((g < (NWG % NGRP)) ? (NWG / NGRP + 1) : (NWG / NGRP));
    unsigned* cnt = barr + g * 64;
    unsigned* root = barr + NGRP * 64;
    unsigned* gen = barr + (NGRP + 1) * 64;
    const unsigned old = __hip_atomic_load(gen, __ATOMIC_RELAXED, __HIP_MEMORY_SCOPE_AGENT);
    const unsigned a = __hip_atomic_fetch_add(cnt, 1u, __ATOMIC_ACQ_REL, __HIP_MEMORY_SCOPE_AGENT);
    if (a == gsz - 1u) {
      __hip_atomic_store(cnt, 0u, __ATOMIC_RELAXED, __HIP_MEMORY_SCOPE_AGENT);
      const unsigned ra = __hip_atomic_fetch_add(root, 1u, __ATOMIC_ACQ_REL, __HIP_MEMORY_SCOPE_AGENT);
      if (ra == (unsigned)(NGRP - 1)) {
        __hip_atomic_store(root, 0u, __ATOMIC_RELAXED, __HIP_MEMORY_SCOPE_AGENT);
        __hip_atomic_fetch_add(gen, 1u, __ATOMIC_RELEASE, __HIP_MEMORY_SCOPE_AGENT);
      }
    }
    int guard = 0;
    while (__hip_atomic_load(gen, __ATOMIC_RELAXED, __HIP_MEMORY_SCOPE_AGENT) == old) {
      __builtin_amdgcn_s_sleep(2);
      if (++guard > 50000000) break;  // failsafe against deadlock-hang
    }
  }
  __syncthreads();
  __threadfence();
}

DI float sigm(float v) { return 1.f / (1.f + expf(-v)); }

// ---- LSTM roles (1,2,3). WG = m-block 32 x j-block 16 (4 gate tiles). ----
template <int ROLE, int PITCH, int KPW>
DI void lstm_role(char* ws, char* smem, int sub) {
  const int tid = threadIdx.x;
  const int wave = tid >> 6, lane = tid & 63, ln16 = lane & 15, quad = lane >> 4;
  const int mb = sub / 25, jb = sub % 25;
  const int m0 = mb * 32;
  const f16* Wsrc = (const f16*)(ws + (ROLE == 1 ? OFF_W1 : ROLE == 2 ? OFF_W2 : OFF_W3));
  const float* bs = (const float*)(ws + (ROLE == 1 ? OFF_BS1 : ROLE == 2 ? OFF_BS2 : OFF_BS3));
  f16* A1 = (f16*)(ws + OFF_A1);
  f16* A2 = (f16*)(ws + OFF_A2);
  f16* A3 = (f16*)(ws + OFF_A3);
  f16* AM = (f16*)(ws + OFF_AM);
  unsigned* barr = (unsigned*)(ws + OFF_BAR);
  float* red = (float*)smem;               // 32KB: [wave][mt][nt][col16][row16]
  float* cst = (float*)(smem + 32768);     // 512 fp32 cell state (persistent!)
  float* bL = (float*)(smem + 32768 + 2048);  // 64 biases

  // preload weight tile as MFMA B-fragments (registers, live whole kernel)
  f16x8 wreg[KPW][4];
#pragma unroll
  for (int i = 0; i < KPW; ++i) {
    const int ks = wave * KPW + i;
#pragma unroll
    for (int nt = 0; nt < 4; ++nt) {
      const int row = nt * Hn + jb * 16 + ln16;
      wreg[i][nt] = *(const f16x8*)(Wsrc + (size_t)row * PITCH + ks * 32 + quad * 8);
    }
  }
  if (tid < 64) bL[tid] = bs[(tid >> 4) * Hn + jb * 16 + (tid & 15)];
  for (int z = tid; z < 512; z += 256) cst[z] = 0.f;
  __syncthreads();

  for (int t = 0; t <= Tn; ++t) {
    const int p = t & 1, q = p ^ 1;
    auto do_slot = [&](const f16* Ain) {
      f32x4 acc[2][4];
#pragma unroll
      for (int mt = 0; mt < 2; ++mt)
#pragma unroll
        for (int nt = 0; nt < 4; ++nt) acc[mt][nt] = f32x4{0.f, 0.f, 0.f, 0.f};
#pragma unroll
      for (int i = 0; i < KPW; ++i) {
        const int kc = (wave * KPW + i) * 32 + quad * 8;
        const f16x8 a0 = *(const f16x8*)(Ain + (m0 + ln16) * PITCH + kc);
        const f16x8 a1 = *(const f16x8*)(Ain + (m0 + 16 + ln16) * PITCH + kc);
#pragma unroll
        for (int nt = 0; nt < 4; ++nt) {
          acc[0][nt] = __builtin_amdgcn_mfma_f32_16x16x32_f16(a0, wreg[i][nt], acc[0][nt], 0, 0, 0);
          acc[1][nt] = __builtin_amdgcn_mfma_f32_16x16x32_f16(a1, wreg[i][nt], acc[1][nt], 0, 0, 0);
        }
      }
#pragma unroll
      for (int mt = 0; mt < 2; ++mt)
#pragma unroll
        for (int nt = 0; nt < 4; ++nt)
          *(f32x4*)&red[(((wave * 2 + mt) * 4 + nt) << 8) + (ln16 << 4) + (quad << 2)] = acc[mt][nt];
      __syncthreads();
#pragma unroll
      for (int e = 0; e < 2; ++e) {
        const int oi = tid * 2 + e;             // 512 (m,j) outputs
        const int m = oi & 31, jj = oi >> 5;
        const int mt = m >> 4, mr = m & 15;
        float s0 = bL[jj], s1 = bL[16 + jj], s2 = bL[32 + jj], s3 = bL[48 + jj];
#pragma unroll
        for (int wv = 0; wv < 4; ++wv) {
          const int bwi = ((wv * 2 + mt) << 10) + (jj << 4) + mr;
          s0 += red[bwi];
          s1 += red[bwi + (1 << 8)];
          s2 += red[bwi + (2 << 8)];
          s3 += red[bwi + (3 << 8)];
        }
        const float iv = sigm(s0), fv = sigm(s1), gv = tanhf(s2), ov = sigm(s3);
        const float c = fv * cst[oi] + iv * gv;
        cst[oi] = c;
        const f16 hb = (f16)(ov * tanhf(c));
        const int bi = m0 + m, ji = jb * 16 + jj;
        if constexpr (ROLE == 1) {
          A1[(size_t)q * 64 * P1 + bi * P1 + 64 + ji] = hb;   // for LSTM1(t+1)
          A2[(size_t)p * 64 * P2 + bi * P2 + 64 + ji] = hb;   // for LSTM2(t)
          AM[(size_t)p * 64 * PM + bi * PM + ji] = hb;        // for OUT(t)
        } else if constexpr (ROLE == 2) {
          A3[(size_t)p * 64 * P2 + bi * P2 + 64 + ji] = hb;   // for LSTM3(t)
          A2[(size_t)q * 64 * P2 + bi * P2 + 480 + ji] = hb;  // rec for LSTM2(t+1)
          AM[(size_t)p * 64 * PM + bi * PM + Hn + ji] = hb;
        } else {
          A3[(size_t)q * 64 * P2 + bi * P2 + 480 + ji] = hb;  // rec for LSTM3(t+1)
          AM[(size_t)p * 64 * PM + bi * PM + 2 * Hn + ji] = hb;
        }
      }
    };
    // slot1: LSTM1
    if (ROLE == 1 && t < Tn) do_slot(A1 + (size_t)p * 64 * P1);
    gridbar(barr);
    // slot2: (attention / output roles work here)
    gridbar(barr);
    // slot3: LSTM2
    if (ROLE == 2 && t < Tn) do_slot(A2 + (size_t)p * 64 * P2);
    gridbar(barr);
    // slot4: LSTM3
    if (ROLE == 3 && t < Tn) do_slot(A3 + (size_t)p * 64 * P2);
    gridbar(barr);
  }
}

// ---- attention role: one WG per batch element ----
DI void att_role(char* ws, char* smem, const float* x, const float* Ww, int b) {
  const int tid = threadIdx.x;
  f16* A1 = (f16*)(ws + OFF_A1);
  f16* A2 = (f16*)(ws + OFF_A2);
  f16* A3 = (f16*)(ws + OFF_A3);
  const f16* teb = (const f16*)(ws + OFF_TEB) + (size_t)b * Un * CD;
  unsigned* barr = (unsigned*)(ws + OFF_BAR);
  float* WwL = (float*)smem;                     // 30*400 fp32 = 48000B
  f16* tebL = (f16*)(smem + 48000);              // 96*64 f16 = 12288B
  float* ps = (float*)(smem + 48000 + 12288);    // 240
  float* pL = ps + 240;                          // 30
  float* alL = pL + 30;                          // 10
  float* beL = alL + 10;                         // 10
  float* kapL = beL + 10;                        // 10 (persistent kappa state)
  float* phiL = kapL + 10;                       // 96
  float* bwL = phiL + 96;                        // 32
  for (int i = tid; i < 12000; i += 256) WwL[i] = Ww[i];
  for (int i = tid; i < Un * CD; i += 256) tebL[i] = teb[i];
  if (tid < 32) bwL[tid] = ((const float*)(ws + OFF_BW))[tid];
  if (tid < 10) kapL[tid] = 0.f;
  __syncthreads();

  for (int t = 0; t <= Tn; ++t) {
    const int p = t & 1, q = p ^ 1;
    gridbar(barr);  // end of slot1: h1(t) visible
    if (t < Tn) {
      const f16* h1p = (const f16*)(ws + OFF_A2) + (size_t)p * 64 * P2 + b * P2 + 64;
      if (tid < 240) {  // p = h1 @ Ww^T : 30 rows x 8 partials of 50
        const int r = tid >> 3, s = tid & 7;
        const float* wr = WwL + r * 400 + s * 50;
        const f16* hp = h1p + s * 50;
        float a = 0.f;
        for (int k = 0; k < 50; ++k) a += wr[k] * (float)hp[k];
        ps[tid] = a;
      }
      __syncthreads();
      if (tid < 30) {
        float v = bwL[tid];
        for (int s = 0; s < 8; ++s) v += ps[tid * 8 + s];
        pL[tid] = v;
      }
      __syncthreads();
      if (tid < 10) {
        alL[tid] = expf(pL[tid]);
        beL[tid] = expf(pL[10 + tid]);
        const float kh = fminf(5.f, fmaxf(-10.f, pL[20 + tid]));
        kapL[tid] += expf(kh);
      }
      __syncthreads();
      if (tid < 96) {
        const float u1 = (float)(tid + 1);
        float s = 0.f;
        for (int k = 0; k < 10; ++k) {
          const float d = kapL[k] - u1;
          s += alL[k] * expf(-beL[k] * d * d);
        }
        phiL[tid] = s;
      }
      __syncthreads();
      if (tid < 64) {  // w = phi @ text_enc
        float wv = 0.f;
        for (int u = 0; u < Un; ++u) wv += phiL[u] * (float)tebL[u * CD + tid];
        const f16 wb = (f16)wv;
        A1[(size_t)q * 64 * P1 + b * P1 + tid] = wb;  // for LSTM1(t+1)
        A2[(size_t)p * 64 * P2 + b * P2 + tid] = wb;  // for LSTM2(t)
        A3[(size_t)p * 64 * P2 + b * P2 + tid] = wb;  // for LSTM3(t)
      }
      if (t + 1 < Tn && tid < 3) {  // stage x(t+1) into next-parity buffers
        const f16 xb = (f16)x[((size_t)b * Tn + t + 1) * 3 + tid];
        A1[(size_t)q * 64 * P1 + b * P1 + 464 + tid] = xb;
        A2[(size_t)q * 64 * P2 + b * P2 + 464 + tid] = xb;
        A3[(size_t)q * 64 * P2 + b * P2 + 464 + tid] = xb;
      }
    }
    gridbar(barr);
    gridbar(barr);
    gridbar(barr);
  }
}

// ---- output projection role: res(t-1) = [h1|h2|h3] @ Wm^T, 16 WGs ----
DI void out_role(char* ws, char* smem, int sub) {
  const int tid = threadIdx.x;
  const int wave = tid >> 6, lane = tid & 63, ln16 = lane & 15, quad = lane >> 4;
  const int mh = sub >> 3, nt = sub & 7;
  const int m0 = mh * 32;
  const f16* Wm = (const f16*)(ws + OFF_WM);
  const f16* AM = (const f16*)(ws + OFF_AM);
  float* resb = (float*)(ws + OFF_RES);
  unsigned* barr = (unsigned*)(ws + OFF_BAR);
  float* red = (float*)smem;             // 8KB
  float* bmL = (float*)(smem + 8192);    // 16
  f16x8 wm[KPWM];
#pragma unroll
  for (int i = 0; i < KPWM; ++i) {
    const int ks = wave * KPWM + i;
    wm[i] = *(const f16x8*)(Wm + (size_t)(nt * 16 + ln16) * PM + ks * 32 + quad * 8);
  }
  if (tid < 16) bmL[tid] = ((const float*)(ws + OFF_BM))[nt * 16 + tid];
  __syncthreads();

  for (int t = 0; t <= Tn; ++t) {
    gridbar(barr);
    if (t > 0) {
      const int tq = (t - 1) & 1;
      const f16* Ap = AM + (size_t)tq * 64 * PM;
      f32x4 acc[2];
      acc[0] = f32x4{0.f, 0.f, 0.f, 0.f};
      acc[1] = f32x4{0.f, 0.f, 0.f, 0.f};
#pragma unroll
      for (int i = 0; i < KPWM; ++i) {
        const int kc = (wave * KPWM + i) * 32 + quad * 8;
        const f16x8 a0 = *(const f16x8*)(Ap + (m0 + ln16) * PM + kc);
        const f16x8 a1 = *(const f16x8*)(Ap + (m0 + 16 + ln16) * PM + kc);
        acc[0] = __builtin_amdgcn_mfma_f32_16x16x32_f16(a0, wm[i], acc[0], 0, 0, 0);
        acc[1] = __builtin_amdgcn_mfma_f32_16x16x32_f16(a1, wm[i], acc[1], 0, 0, 0);
      }
#pragma unroll
      for (int mt = 0; mt < 2; ++mt)
        *(f32x4*)&red[((wave * 2 + mt) << 8) + (ln16 << 4) + (quad << 2)] = acc[mt];
      __syncthreads();
#pragma unroll
      for (int e = 0; e < 2; ++e) {
        const int oi = tid * 2 + e;
        const int m = oi & 31, cc = oi >> 5;
        const int mt = m >> 4, mr = m & 15;
        float v = bmL[cc];
#pragma unroll
        for (int wv = 0; wv < 4; ++wv) v += red[((wv * 2 + mt) << 8) + (cc << 4) + mr];
        resb[((size_t)(t - 1) * 64 + m0 + m) * 128 + nt * 16 + cc] = v;
      }
      __syncthreads();
    }
    gridbar(barr);
    gridbar(barr);
    gridbar(barr);
  }
}

__global__ void __launch_bounds__(256, 1) coop_kernel(char* ws, const float* x, const float* Ww) {
  __shared__ char smem[62464];
  const int id = (int)blockIdx.x;
  if (id < 50) lstm_role<1, P1, KPW1>(ws, smem, id);
  else if (id < 100) lstm_role<2, P2, KPW2>(ws, smem, id - 50);
  else if (id < 150) lstm_role<3, P2, KPW2>(ws, smem, id - 100);
  else if (id < 214) att_role(ws, smem, x, Ww, id - 150);
  else out_role(ws, smem, id - 214);
}

// ---- init: build f16 weight layouts, zero A-buffers, gather text emb ----
__global__ void init_build(char* ws, const float* x, const int* tok, const float* emb,
                           const float* Wih1, const float* Whh1, const float* bih1, const float* bhh1,
                           const float* Wih2, const float* Whh2, const float* bih2, const float* bhh2,
                           const float* Wih3, const float* Whh3, const float* bih3, const float* bhh3,
                           const float* Ww, const float* bw, const float* Wm, const float* bm) {
  const int blk = (int)blockIdx.x, tid = (int)threadIdx.x;
  if (blk < 1600) {
    const int j = blk;
    f16* W1 = (f16*)(ws + OFF_W1) + (size_t)j * P1;
    f16* W2 = (f16*)(ws + OFF_W2) + (size_t)j * P2;
    f16* W3 = (f16*)(ws + OFF_W3) + (size_t)j * P2;
    for (int c = tid; c < P1; c += 256) {
      float v = 0.f;
      if (c < 64) v = Wih1[(size_t)j * 67 + 3 + c];
      else if (c < 464) v = Whh1[(size_t)j * 400 + c - 64];
      else if (c < 467) v = Wih1[(size_t)j * 67 + c - 464];
      W1[c] = (f16)v;
    }
    for (int c = tid; c < P2; c += 256) {
      float v2 = 0.f, v3 = 0.f;
      if (c < 64) { v2 = Wih2[(size_t)j * 467 + 403 + c]; v3 = Wih3[(size_t)j * 467 + 403 + c]; }
      else if (c < 464) { v2 = Wih2[(size_t)j * 467 + 3 + c - 64]; v3 = Wih3[(size_t)j * 467 + 3 + c - 64]; }
      else if (c < 467) { v2 = Wih2[(size_t)j * 467 + c - 464]; v3 = Wih3[(size_t)j * 467 + c - 464]; }
      else if (c >= 480 && c < 880) { v2 = Whh2[(size_t)j * 400 + c - 480]; v3 = Whh3[(size_t)j * 400 + c - 480]; }
      W2[c] = (f16)v2;
      W3[c] = (f16)v3;
    }
  } else if (blk < 1728) {
    const int r = blk - 1600;
    f16* WMp = (f16*)(ws + OFF_WM) + (size_t)r * PM;
    for (int c = tid; c < PM; c += 256) {
      const float v = (r < 121 && c < 1200) ? Wm[(size_t)r * 1200 + c] : 0.f;
      WMp[c] = (f16)v;
    }
  } else if (blk == 1728) {
    float* bs1 = (float*)(ws + OFF_BS1);
    float* bs2 = (float*)(ws + OFF_BS2);
    float* bs3 = (float*)(ws + OFF_BS3);
    for (int i = tid; i < 1600; i += 256) {
      bs1[i] = bih1[i] + bhh1[i];
      bs2[i] = bih2[i] + bhh2[i];
      bs3[i] = bih3[i] + bhh3[i];
    }
    float* bwp = (float*)(ws + OFF_BW);
    if (tid < 32) bwp[tid] = (tid < 30) ? bw[tid] : 0.f;
    float* bmp = (float*)(ws + OFF_BM);
    if (tid < 128) bmp[tid] = (tid < 121) ? bm[tid] : 0.f;
    unsigned* barr = (unsigned*)(ws + OFF_BAR);
    for (int i = tid; i < 2048; i += 256) barr[i] = 0u;
  } else if (blk < 1761) {
    unsigned* az = (unsigned*)(ws + OFF_A1);  // A1,A2,A3,AM contiguous
    const int n = (int)((SZ_A1 + 2 * SZ_A2 + SZ_AM) / 4);
    for (int i = (blk - 1729) * 256 + tid; i < n; i += 32 * 256) az[i] = 0u;
  } else {
    f16* tebp = (f16*)(ws + OFF_TEB);
    const int n = 64 * 96 * 64;
    for (int i = (blk - 1761) * 256 + tid; i < n; i += 128 * 256) {
      const int b = i / (96 * 64);
      const int rem = i % (96 * 64);
      const int u = rem >> 6, d = rem & 63;
      const int tk = tok[b * 96 + u];
      tebp[i] = (f16)emb[(size_t)tk * 64 + d];
    }
  }
}

__global__ void init_x0(char* ws, const float* x) {
  const int tid = (int)threadIdx.x;
  if (tid < 192) {
    const int b = tid / 3, k = tid % 3;
    const f16 xv = (f16)x[(size_t)b * Tn * 3 + k];
    ((f16*)(ws + OFF_A1))[(size_t)b * P1 + 464 + k] = xv;
    ((f16*)(ws + OFF_A2))[(size_t)b * P2 + 464 + k] = xv;
    ((f16*)(ws + OFF_A3))[(size_t)b * P2 + 464 + k] = xv;
  }
}

// ---- epilogue: res -> (eos, softmax pi, mu, sigma, rho) ----
__global__ void postproc(const char* ws, float* out) {
  __shared__ float r[50 * 128];
  __shared__ float mx[50], dn[50];
  const float* resb = (const float*)(ws + OFF_RES);
  const int tid = (int)threadIdx.x;
  const int b = (int)blockIdx.x >> 4;
  const int t0 = ((int)blockIdx.x & 15) * 50;
  for (int idx = tid; idx < 50 * 128; idx += 256) {
    const int tt = idx >> 7, c = idx & 127;
    r[idx] = resb[((size_t)(t0 + tt) * 64 + b) * 128 + c];
  }
  __syncthreads();
  if (tid < 50) {
    float m = -1e30f;
    for (int k = 0; k < 20; ++k) m = fmaxf(m, r[tid * 128 + 1 + k]);
    float s = 0.f;
    for (int k = 0; k < 20; ++k) s += expf(r[tid * 128 + 1 + k] - m);
    mx[tid] = m;
    dn[tid] = 1.f / s;
  }
  __syncthreads();
  for (int idx = tid; idx < 50; idx += 256)
    out[O_EOS + (size_t)b * Tn + t0 + idx] = r[idx * 128];
  for (int idx = tid; idx < 50 * 20; idx += 256) {
    const int tt = idx / 20, k = idx % 20;
    const size_t o = ((size_t)b * Tn + t0 + tt) * 20 + k;
    const float* rr = &r[tt * 128];
    out[O_PI + o] = expf(rr[1 + k] - mx[tt]) * dn[tt];
    out[O_MUX + o] = rr[21 + k];
    out[O_MUY + o] = rr[41 + k];
    out[O_SX + o] = expf(rr[61 + k]) + 1e-6f;
    out[O_SY + o] = expf(rr[81 + k]) + 1e-6f;
    out[O_RHO + o] = tanhf(rr[101 + k]) * 0.999f;
  }
}

extern "C" void kernel_launch(void* const* d_in, const int* in_sizes, int n_in,
                              void* d_out, int out_size, void* d_ws, size_t ws_size,
                              hipStream_t stream) {
  const float* x = (const float*)d_in[0];
  const int* tok = (const int*)d_in[1];
  const float* emb = (const float*)d_in[2];
  const float* Wih1 = (const float*)d_in[3];
  const float* Whh1 = (const float*)d_in[4];
  const float* bih1 = (const float*)d_in[5];
  const float* bhh1 = (const float*)d_in[6];
  const float* Wih2 = (const float*)d_in[7];
  const float* Whh2 = (const float*)d_in[8];
  const float* bih2 = (const float*)d_in[9];
  const float* bhh2 = (const float*)d_in[10];
  const float* Wih3 = (const float*)d_in[11];
  const float* Whh3 = (const float*)d_in[12];
  const float* bih3 = (const float*)d_in[13];
  const float* bhh3 = (const float*)d_in[14];
  const float* Ww = (const float*)d_in[15];
  const float* bw = (const float*)d_in[16];
  const float* Wm = (const float*)d_in[17];
  const float* bm = (const float*)d_in[18];
  char* ws = (char*)d_ws;
  float* out = (float*)d_out;

  hipLaunchKernelGGL(init_build, dim3(1889), dim3(256), 0, stream,
                     ws, x, tok, emb, Wih1, Whh1, bih1, bhh1, Wih2, Whh2, bih2, bhh2,
                     Wih3, Whh3, bih3, bhh3, Ww, bw, Wm, bm);
  hipLaunchKernelGGL(init_x0, dim3(1), dim3(256), 0, stream, ws, x);

  char* ws_arg = ws;
  const float* x_arg = x;
  const float* ww_arg = Ww;
  void* kargs[] = {&ws_arg, &x_arg, &ww_arg};
  hipLaunchCooperativeKernel((const void*)coop_kernel, dim3(NWG), dim3(256), kargs, 0, stream);

  hipLaunchKernelGGL(postproc, dim3(1024), dim3(256), 0, stream, ws, out);
}

// Round 3
// 45102.951 us; speedup vs baseline: 2.2357x; 2.2357x over previous
//
#include <hip/hip_runtime.h>

// ============================================================================
// R3: revert to R1's proven 4-slot schedule; lean barrier (thread0 release-RMW
// arrival + per-wave acquire-fence exit); 107 WGs; coop-launch fallback.
// Label: "R3 coop 4-slot, lean barrier, 107WG, fallback"
// ============================================================================

#define DI __device__ __forceinline__

typedef _Float16 f16;
typedef _Float16 f16x8 __attribute__((ext_vector_type(8)));
typedef _Float16 f16x4 __attribute__((ext_vector_type(4)));
typedef float f32x4 __attribute__((ext_vector_type(4)));

constexpr int Bn = 64, Tn = 800, Un = 96, CD = 64, Hn = 400;
// K-layouts (f16, zero-padded to 32-multiples):
//  A1/W1: [w 64 | h1 400 | x 3 | 0..] P1=520, ks 0..15
//  A2/W2: [w 64 | h1 400 | x 3 | 0(13) | h2rec 400 | 0..] P2=904, ks 0..27
//  A3/W3: [w 64 | h2 400 | x 3 | 0(13) | h3rec 400 | 0..] P3=904, ks 0..27
//  AM/WM: [h1 400 | h2 400 | h3 400 | 0(88)] PM=1288, ks 0..39
constexpr int P1 = 520, P2 = 904, P3 = 904, PM = 1288, KPWM = 10;
constexpr int NWG = 107, NGRP = 8;

constexpr size_t OFF_W1 = 0;
constexpr size_t SZ_W1 = (size_t)1600 * P1 * 2;
constexpr size_t OFF_W2 = OFF_W1 + SZ_W1;
constexpr size_t SZ_W2 = (size_t)1600 * P2 * 2;
constexpr size_t OFF_W3 = OFF_W2 + SZ_W2;
constexpr size_t OFF_WM = OFF_W3 + SZ_W2;
constexpr size_t SZ_WM = (size_t)128 * PM * 2;
constexpr size_t OFF_A1 = OFF_WM + SZ_WM;
constexpr size_t SZ_A1 = (size_t)2 * 64 * P1 * 2;
constexpr size_t OFF_A2 = OFF_A1 + SZ_A1;
constexpr size_t SZ_A2 = (size_t)2 * 64 * P2 * 2;
constexpr size_t OFF_A3 = OFF_A2 + SZ_A2;
constexpr size_t OFF_AM = OFF_A3 + SZ_A2;
constexpr size_t SZ_AM = (size_t)2 * 64 * PM * 2;
constexpr size_t OFF_TEB = OFF_AM + SZ_AM;
constexpr size_t SZ_TEB = (size_t)64 * 96 * 64 * 2;
constexpr size_t OFF_BS1 = OFF_TEB + SZ_TEB;
constexpr size_t OFF_BS2 = OFF_BS1 + 6400;
constexpr size_t OFF_BS3 = OFF_BS2 + 6400;
constexpr size_t OFF_BW = OFF_BS3 + 6400;
constexpr size_t OFF_BM = OFF_BW + 128;
constexpr size_t OFF_BAR = OFF_BM + 512;
constexpr size_t SZ_BAR = 8192;
constexpr size_t OFF_RES = OFF_BAR + SZ_BAR;

// output offsets (fp32 elements): eos,pi,mux,muy,sx,sy,rho
constexpr size_t O_EOS = 0, O_PI = 51200, O_MUX = 1075200, O_MUY = 2099200;
constexpr size_t O_SX = 3123200, O_SY = 4147200, O_RHO = 5171200;

// ---- lean two-level grid barrier ----
DI void gridbar(unsigned* barr) {
  __syncthreads();  // per-wave s_waitcnt vmcnt(0) before s_barrier: WG stores in L2
  if (threadIdx.x == 0) {
    const int g = (int)(blockIdx.x & (NGRP - 1));
    const unsigned gsz = (unsigned)((g < (NWG % NGRP)) ? (NWG / NGRP + 1) : (NWG / NGRP));
    unsigned* cnt = barr + g * 32;
    unsigned* root = barr + NGRP * 32;
    unsigned* gen = barr + (NGRP + 1) * 32;
    const unsigned old = __hip_atomic_load(gen, __ATOMIC_RELAXED, __HIP_MEMORY_SCOPE_AGENT);
    const unsigned a = __hip_atomic_fetch_add(cnt, 1u, __ATOMIC_RELEASE, __HIP_MEMORY_SCOPE_AGENT);
    if (a == gsz - 1u) {
      __builtin_amdgcn_fence(__ATOMIC_ACQUIRE, "agent");
      __hip_atomic_store(cnt, 0u, __ATOMIC_RELAXED, __HIP_MEMORY_SCOPE_AGENT);
      const unsigned ra = __hip_atomic_fetch_add(root, 1u, __ATOMIC_RELEASE, __HIP_MEMORY_SCOPE_AGENT);
      if (ra == (unsigned)(NGRP - 1)) {
        __builtin_amdgcn_fence(__ATOMIC_ACQUIRE, "agent");
        __hip_atomic_store(root, 0u, __ATOMIC_RELAXED, __HIP_MEMORY_SCOPE_AGENT);
        __hip_atomic_fetch_add(gen, 1u, __ATOMIC_RELEASE, __HIP_MEMORY_SCOPE_AGENT);
      }
    }
    int guard = 0;
    while (__hip_atomic_load(gen, __ATOMIC_RELAXED, __HIP_MEMORY_SCOPE_AGENT) == old) {
      __builtin_amdgcn_s_sleep(4);
      if (++guard > 20000000) break;  // failsafe
    }
  }
  __syncthreads();
  __builtin_amdgcn_fence(__ATOMIC_ACQUIRE, "agent");  // per-wave L1/L2 inv
}

DI float sigm(float v) { return 1.f / (1.f + expf(-v)); }

// ---- shared LSTM slot: wave-per-gate, m=64, j-tile=16; dC may be nullptr ----
template <int KS, int PITCH>
DI void lstm_slot(const f16x8* wr, const f16* Ain, char* smem, int tid,
                  const float* bL, float* cst,
                  f16* dA, int pA, f16* dB, int pB, f16* dC, int pC) {
  const int wave = tid >> 6, lane = tid & 63, ln16 = lane & 15, quad = lane >> 4;
  float* red = (float*)smem;  // [gate 4][b 64][j 16]
  f32x4 acc[4];
#pragma unroll
  for (int mt = 0; mt < 4; ++mt) acc[mt] = f32x4{0.f, 0.f, 0.f, 0.f};
#pragma unroll
  for (int i = 0; i < KS; ++i) {
    const int kc = i * 32 + quad * 8;
#pragma unroll
    for (int mt = 0; mt < 4; ++mt) {
      const f16x8 a = *(const f16x8*)(Ain + (mt * 16 + ln16) * PITCH + kc);
      acc[mt] = __builtin_amdgcn_mfma_f32_16x16x32_f16(a, wr[i], acc[mt], 0, 0, 0);
    }
  }
#pragma unroll
  for (int mt = 0; mt < 4; ++mt)
#pragma unroll
    for (int r = 0; r < 4; ++r)
      red[wave * 1024 + (mt * 16 + quad * 4 + r) * 16 + ln16] = acc[mt][r];
  __syncthreads();
  {
    const int oi = tid * 4, b = oi >> 4, j0 = oi & 15;
    f32x4 gi = *(f32x4*)&red[oi];
    f32x4 gf = *(f32x4*)&red[1024 + oi];
    f32x4 gg = *(f32x4*)&red[2048 + oi];
    f32x4 go = *(f32x4*)&red[3072 + oi];
    f32x4 c = *(f32x4*)&cst[oi];
    f16x4 hv;
#pragma unroll
    for (int e = 0; e < 4; ++e) {
      const float iv = sigm(gi[e] + bL[j0 + e]);
      const float fv = sigm(gf[e] + bL[16 + j0 + e]);
      const float gv = tanhf(gg[e] + bL[32 + j0 + e]);
      const float ov = sigm(go[e] + bL[48 + j0 + e]);
      const float cn = fv * c[e] + iv * gv;
      c[e] = cn;
      hv[e] = (f16)(ov * tanhf(cn));
    }
    *(f32x4*)&cst[oi] = c;
    *(f16x4*)(dA + b * pA + j0) = hv;
    *(f16x4*)(dB + b * pB + j0) = hv;
    if (dC != nullptr) *(f16x4*)(dC + b * pC + j0) = hv;
  }
  __syncthreads();
}

// ---- LSTM1 role (25 WGs): slot1 ----
DI void l1_role(char* ws, char* smem, int jb) {
  const int tid = threadIdx.x;
  const int wave = tid >> 6, lane = tid & 63, ln16 = lane & 15, quad = lane >> 4;
  const f16* W1 = (const f16*)(ws + OFF_W1);
  f16* A1 = (f16*)(ws + OFF_A1);
  f16* A2 = (f16*)(ws + OFF_A2);
  f16* AM = (f16*)(ws + OFF_AM);
  unsigned* barr = (unsigned*)(ws + OFF_BAR);
  float* cst = (float*)(smem + 16384);
  float* bL = (float*)(smem + 20480);
  const int row = wave * Hn + jb * 16 + ln16;
  f16x8 wr[16];
#pragma unroll
  for (int i = 0; i < 16; ++i) wr[i] = *(const f16x8*)(W1 + (size_t)row * P1 + i * 32 + quad * 8);
  if (tid < 64) bL[tid] = ((const float*)(ws + OFF_BS1))[(tid >> 4) * Hn + jb * 16 + (tid & 15)];
  for (int z = tid; z < 1024; z += 256) cst[z] = 0.f;
  __syncthreads();
  for (int t = 0;; ++t) {
    if (t < Tn)
      lstm_slot<16, P1>(wr, A1 + (size_t)(t & 1) * 64 * P1, smem, tid, bL, cst,
                        A1 + (size_t)((t + 1) & 1) * 64 * P1 + 64 + jb * 16, P1,
                        A2 + (size_t)(t & 1) * 64 * P2 + 64 + jb * 16, P2,
                        AM + (size_t)(t & 1) * 64 * PM + jb * 16, PM);
    gridbar(barr);
    if (t == Tn) break;
    gridbar(barr);
    gridbar(barr);
    gridbar(barr);
  }
}

// ---- LSTM2 role (25 WGs): slot3 ----
DI void l2_role(char* ws, char* smem, int jb) {
  const int tid = threadIdx.x;
  const int wave = tid >> 6, lane = tid & 63, ln16 = lane & 15, quad = lane >> 4;
  const f16* W2 = (const f16*)(ws + OFF_W2);
  f16* A2 = (f16*)(ws + OFF_A2);
  f16* A3 = (f16*)(ws + OFF_A3);
  f16* AM = (f16*)(ws + OFF_AM);
  unsigned* barr = (unsigned*)(ws + OFF_BAR);
  float* cst = (float*)(smem + 16384);
  float* bL = (float*)(smem + 20480);
  const int row = wave * Hn + jb * 16 + ln16;
  f16x8 wr[28];
#pragma unroll
  for (int i = 0; i < 28; ++i) wr[i] = *(const f16x8*)(W2 + (size_t)row * P2 + i * 32 + quad * 8);
  if (tid < 64) bL[tid] = ((const float*)(ws + OFF_BS2))[(tid >> 4) * Hn + jb * 16 + (tid & 15)];
  for (int z = tid; z < 1024; z += 256) cst[z] = 0.f;
  __syncthreads();
  for (int t = 0;; ++t) {
    gridbar(barr);
    if (t == Tn) break;
    gridbar(barr);
    lstm_slot<28, P2>(wr, A2 + (size_t)(t & 1) * 64 * P2, smem, tid, bL, cst,
                      A2 + (size_t)((t + 1) & 1) * 64 * P2 + 480 + jb * 16, P2,
                      A3 + (size_t)(t & 1) * 64 * P3 + 64 + jb * 16, P3,
                      AM + (size_t)(t & 1) * 64 * PM + Hn + jb * 16, PM);
    gridbar(barr);
    gridbar(barr);
  }
}

// ---- LSTM3 role (25 WGs): slot4 ----
DI void l3_role(char* ws, char* smem, int jb) {
  const int tid = threadIdx.x;
  const int wave = tid >> 6, lane = tid & 63, ln16 = lane & 15, quad = lane >> 4;
  const f16* W3 = (const f16*)(ws + OFF_W3);
  f16* A3 = (f16*)(ws + OFF_A3);
  f16* AM = (f16*)(ws + OFF_AM);
  unsigned* barr = (unsigned*)(ws + OFF_BAR);
  float* cst = (float*)(smem + 16384);
  float* bL = (float*)(smem + 20480);
  const int row = wave * Hn + jb * 16 + ln16;
  f16x8 wr[28];
#pragma unroll
  for (int i = 0; i < 28; ++i) wr[i] = *(const f16x8*)(W3 + (size_t)row * P3 + i * 32 + quad * 8);
  if (tid < 64) bL[tid] = ((const float*)(ws + OFF_BS3))[(tid >> 4) * Hn + jb * 16 + (tid & 15)];
  for (int z = tid; z < 1024; z += 256) cst[z] = 0.f;
  __syncthreads();
  for (int t = 0;; ++t) {
    gridbar(barr);
    if (t == Tn) break;
    gridbar(barr);
    gridbar(barr);
    lstm_slot<28, P3>(wr, A3 + (size_t)(t & 1) * 64 * P3, smem, tid, bL, cst,
                      A3 + (size_t)((t + 1) & 1) * 64 * P3 + 480 + jb * 16, P3,
                      AM + (size_t)(t & 1) * 64 * PM + 2 * Hn + jb * 16, PM,
                      nullptr, 0);
    gridbar(barr);
  }
}

// ---- attention role (16 WGs x 4 batches): slot2 ----
DI void att_role(char* ws, char* smem, int ab, const float* x, const float* Ww) {
  const int tid = threadIdx.x;
  const int b0 = ab * 4;
  f16* A1 = (f16*)(ws + OFF_A1);
  f16* A2 = (f16*)(ws + OFF_A2);
  f16* A3 = (f16*)(ws + OFF_A3);
  unsigned* barr = (unsigned*)(ws + OFF_BAR);
  f16* tebL = (f16*)smem;                 // 4*96*64 f16 = 49152
  f16* h1L = (f16*)(smem + 49152);        // 1600 f16
  float* ps = (float*)(smem + 52352);     // 960
  float* pL = (float*)(smem + 56192);     // 120
  float* aL = (float*)(smem + 56672);     // 40
  float* beL = (float*)(smem + 56832);    // 40
  float* kaL = (float*)(smem + 56992);    // 40 (persistent kappa)
  float* phiL = (float*)(smem + 57152);   // 384
  float* bwL = (float*)(smem + 58688);    // 30
  const int pr = tid >> 3, psd = tid & 7;
  float wwr[50];
  if (tid < 240) {
#pragma unroll
    for (int k = 0; k < 50; ++k) wwr[k] = Ww[pr * 400 + psd * 50 + k];
  }
  for (int i = tid; i < 24576; i += 256)
    tebL[i] = ((const f16*)(ws + OFF_TEB))[(size_t)b0 * 6144 + i];
  if (tid < 40) kaL[tid] = 0.f;
  if (tid < 30) bwL[tid] = ((const float*)(ws + OFF_BW))[tid];
  __syncthreads();

  for (int t = 0;; ++t) {
    gridbar(barr);  // end slot1: h1(t) visible
    if (t < Tn) {
      const f16* h1p = A2 + (size_t)(t & 1) * 64 * P2;
      for (int i = tid; i < 1600; i += 256) {
        const int b = i / 400, k = i % 400;
        h1L[i] = h1p[(b0 + b) * P2 + 64 + k];
      }
      __syncthreads();
      if (tid < 240) {
#pragma unroll 1
        for (int b = 0; b < 4; ++b) {
          const f16* hh = &h1L[b * 400 + psd * 50];
          float a = 0.f;
#pragma unroll
          for (int k = 0; k < 50; ++k) a += wwr[k] * (float)hh[k];
          ps[(b * 30 + pr) * 8 + psd] = a;
        }
      }
      __syncthreads();
      if (tid < 120) {
        const int b = tid / 30, r = tid % 30;
        float v = bwL[r];
#pragma unroll
        for (int s = 0; s < 8; ++s) v += ps[(b * 30 + r) * 8 + s];
        pL[b * 30 + r] = v;
      }
      __syncthreads();
      if (tid < 40) {
        const int b = tid / 10, k = tid % 10;
        aL[tid] = expf(pL[b * 30 + k]);
        beL[tid] = expf(pL[b * 30 + 10 + k]);
        kaL[tid] += expf(fminf(5.f, fmaxf(-10.f, pL[b * 30 + 20 + k])));
      }
      __syncthreads();
      for (int idx = tid; idx < 384; idx += 256) {
        const int b = idx / 96;
        const float u1 = (float)(idx % 96 + 1);
        float s = 0.f;
#pragma unroll
        for (int k = 0; k < 10; ++k) {
          const float d = kaL[b * 10 + k] - u1;
          s += aL[b * 10 + k] * expf(-beL[b * 10 + k] * d * d);
        }
        phiL[idx] = s;
      }
      __syncthreads();
      {
        const int b = tid >> 6, d = tid & 63;
        float wv = 0.f;
        for (int u = 0; u < 96; ++u) wv += phiL[b * 96 + u] * (float)tebL[(b * 96 + u) * 64 + d];
        const f16 wb = (f16)wv;
        const int bg = b0 + b;
        A2[(size_t)(t & 1) * 64 * P2 + bg * P2 + d] = wb;             // LSTM2(t), slot3
        A3[(size_t)(t & 1) * 64 * P3 + bg * P3 + d] = wb;             // LSTM3(t), slot4
        A1[(size_t)((t + 1) & 1) * 64 * P1 + bg * P1 + d] = wb;       // LSTM1(t+1)
      }
      if (t + 1 < Tn && tid < 12) {
        const int b = b0 + tid / 3, k = tid % 3;
        const f16 xb = (f16)x[((size_t)b * Tn + (t + 1)) * 3 + k];
        A1[(size_t)((t + 1) & 1) * 64 * P1 + b * P1 + 464 + k] = xb;
        A2[(size_t)((t + 1) & 1) * 64 * P2 + b * P2 + 464 + k] = xb;
        A3[(size_t)((t + 1) & 1) * 64 * P3 + b * P3 + 464 + k] = xb;
      }
    }
    if (t == Tn) break;
    gridbar(barr);
    gridbar(barr);
    gridbar(barr);
  }
}

// ---- output projection role (16 WGs): slot2, res(t-1) ----
DI void out_role(char* ws, char* smem, int sub) {
  const int tid = threadIdx.x;
  const int wave = tid >> 6, lane = tid & 63, ln16 = lane & 15, quad = lane >> 4;
  const int mh = sub >> 3, nt = sub & 7;
  const int m0 = mh * 32;
  const f16* WM = (const f16*)(ws + OFF_WM);
  const f16* AM = (const f16*)(ws + OFF_AM);
  float* resb = (float*)(ws + OFF_RES);
  unsigned* barr = (unsigned*)(ws + OFF_BAR);
  float* red = (float*)smem;             // 8KB
  float* bmL = (float*)(smem + 8192);    // 16
  f16x8 wm[KPWM];
#pragma unroll
  for (int i = 0; i < KPWM; ++i) {
    const int ks = wave * KPWM + i;
    wm[i] = *(const f16x8*)(WM + (size_t)(nt * 16 + ln16) * PM + ks * 32 + quad * 8);
  }
  if (tid < 16) bmL[tid] = ((const float*)(ws + OFF_BM))[nt * 16 + tid];
  __syncthreads();

  for (int t = 0;; ++t) {
    gridbar(barr);
    if (t >= 1) {
      const f16* Ap = AM + (size_t)((t - 1) & 1) * 64 * PM;
      f32x4 acc[2];
      acc[0] = f32x4{0.f, 0.f, 0.f, 0.f};
      acc[1] = f32x4{0.f, 0.f, 0.f, 0.f};
#pragma unroll
      for (int i = 0; i < KPWM; ++i) {
        const int kc = (wave * KPWM + i) * 32 + quad * 8;
        const f16x8 a0 = *(const f16x8*)(Ap + (m0 + ln16) * PM + kc);
        const f16x8 a1 = *(const f16x8*)(Ap + (m0 + 16 + ln16) * PM + kc);
        acc[0] = __builtin_amdgcn_mfma_f32_16x16x32_f16(a0, wm[i], acc[0], 0, 0, 0);
        acc[1] = __builtin_amdgcn_mfma_f32_16x16x32_f16(a1, wm[i], acc[1], 0, 0, 0);
      }
#pragma unroll
      for (int mt = 0; mt < 2; ++mt)
        *(f32x4*)&red[((wave * 2 + mt) << 8) + (ln16 << 4) + (quad << 2)] = acc[mt];
      __syncthreads();
#pragma unroll
      for (int e = 0; e < 2; ++e) {
        const int oi = tid * 2 + e;
        const int m = oi & 31, cc = oi >> 5;
        const int mt = m >> 4, mr = m & 15;
        float v = bmL[cc];
#pragma unroll
        for (int wv = 0; wv < 4; ++wv) v += red[((wv * 2 + mt) << 8) + (cc << 4) + mr];
        resb[((size_t)(t - 1) * 64 + m0 + m) * 128 + nt * 16 + cc] = v;
      }
      __syncthreads();
    }
    if (t == Tn) break;
    gridbar(barr);
    gridbar(barr);
    gridbar(barr);
  }
}

__global__ void __launch_bounds__(256, 1) coop_kernel(char* ws, const float* x, const float* Ww) {
  __shared__ char smem[59392];
  const int id = (int)blockIdx.x;
  if (id < 25) l1_role(ws, smem, id);
  else if (id < 50) l2_role(ws, smem, id - 25);
  else if (id < 75) l3_role(ws, smem, id - 50);
  else if (id < 91) att_role(ws, smem, id - 75, x, Ww);
  else out_role(ws, smem, id - 91);
}

// ---- init: build f16 weight layouts, zero A-buffers, gather text emb ----
__global__ void init_build(char* ws, const int* tok, const float* emb,
                           const float* Wih1, const float* Whh1, const float* bih1, const float* bhh1,
                           const float* Wih2, const float* Whh2, const float* bih2, const float* bhh2,
                           const float* Wih3, const float* Whh3, const float* bih3, const float* bhh3,
                           const float* bw, const float* Wm, const float* bm) {
  const int blk = (int)blockIdx.x, tid = (int)threadIdx.x;
  if (blk < 1600) {
    const int j = blk;
    f16* W1 = (f16*)(ws + OFF_W1) + (size_t)j * P1;
    f16* W2 = (f16*)(ws + OFF_W2) + (size_t)j * P2;
    f16* W3 = (f16*)(ws + OFF_W3) + (size_t)j * P2;
    for (int c = tid; c < P1; c += 256) {
      float v = 0.f;
      if (c < 64) v = Wih1[(size_t)j * 67 + 3 + c];
      else if (c < 464) v = Whh1[(size_t)j * 400 + c - 64];
      else if (c < 467) v = Wih1[(size_t)j * 67 + c - 464];
      W1[c] = (f16)v;
    }
    for (int c = tid; c < P2; c += 256) {
      float v2 = 0.f, v3 = 0.f;
      if (c < 64) { v2 = Wih2[(size_t)j * 467 + 403 + c]; v3 = Wih3[(size_t)j * 467 + 403 + c]; }
      else if (c < 464) { v2 = Wih2[(size_t)j * 467 + 3 + c - 64]; v3 = Wih3[(size_t)j * 467 + 3 + c - 64]; }
      else if (c < 467) { v2 = Wih2[(size_t)j * 467 + c - 464]; v3 = Wih3[(size_t)j * 467 + c - 464]; }
      else if (c >= 480 && c < 880) { v2 = Whh2[(size_t)j * 400 + c - 480]; v3 = Whh3[(size_t)j * 400 + c - 480]; }
      W2[c] = (f16)v2;
      W3[c] = (f16)v3;
    }
  } else if (blk < 1728) {
    const int r = blk - 1600;
    f16* WMp = (f16*)(ws + OFF_WM) + (size_t)r * PM;
    for (int c = tid; c < PM; c += 256) {
      const float v = (r < 121 && c < 1200) ? Wm[(size_t)r * 1200 + c] : 0.f;
      WMp[c] = (f16)v;
    }
  } else if (blk == 1728) {
    float* bs1 = (float*)(ws + OFF_BS1);
    float* bs2 = (float*)(ws + OFF_BS2);
    float* bs3 = (float*)(ws + OFF_BS3);
    for (int i = tid; i < 1600; i += 256) {
      bs1[i] = bih1[i] + bhh1[i];
      bs2[i] = bih2[i] + bhh2[i];
      bs3[i] = bih3[i] + bhh3[i];
    }
    float* bwp = (float*)(ws + OFF_BW);
    if (tid < 32) bwp[tid] = (tid < 30) ? bw[tid] : 0.f;
    float* bmp = (float*)(ws + OFF_BM);
    if (tid < 128) bmp[tid] = (tid < 121) ? bm[tid] : 0.f;
    unsigned* barr = (unsigned*)(ws + OFF_BAR);
    for (int i = tid; i < 2048; i += 256) barr[i] = 0u;
  } else if (blk < 1761) {
    unsigned* az = (unsigned*)(ws + OFF_A1);  // A1,A2,A3,AM contiguous
    const int n = (int)((SZ_A1 + 2 * SZ_A2 + SZ_AM) / 4);
    for (int i = (blk - 1729) * 256 + tid; i < n; i += 32 * 256) az[i] = 0u;
  } else {
    f16* tebp = (f16*)(ws + OFF_TEB);
    const int n = 64 * 96 * 64;
    for (int i = (blk - 1761) * 256 + tid; i < n; i += 128 * 256) {
      const int b = i / (96 * 64);
      const int rem = i % (96 * 64);
      const int u = rem >> 6, d = rem & 63;
      const int tk = tok[b * 96 + u];
      tebp[i] = (f16)emb[(size_t)tk * 64 + d];
    }
  }
}

__global__ void init_x0(char* ws, const float* x) {
  const int tid = (int)threadIdx.x;
  if (tid < 192) {
    const int b = tid / 3, k = tid % 3;
    const f16 xv = (f16)x[(size_t)b * Tn * 3 + k];
    ((f16*)(ws + OFF_A1))[(size_t)b * P1 + 464 + k] = xv;
    ((f16*)(ws + OFF_A2))[(size_t)b * P2 + 464 + k] = xv;
    ((f16*)(ws + OFF_A3))[(size_t)b * P3 + 464 + k] = xv;
  }
}

// ---- epilogue: res -> (eos, softmax pi, mu, sigma, rho) ----
__global__ void postproc(const char* ws, float* out) {
  __shared__ float r[50 * 128];
  __shared__ float mx[50], dn[50];
  const float* resb = (const float*)(ws + OFF_RES);
  const int tid = (int)threadIdx.x;
  const int b = (int)blockIdx.x >> 4;
  const int t0 = ((int)blockIdx.x & 15) * 50;
  for (int idx = tid; idx < 50 * 128; idx += 256) {
    const int tt = idx >> 7, c = idx & 127;
    r[idx] = resb[((size_t)(t0 + tt) * 64 + b) * 128 + c];
  }
  __syncthreads();
  if (tid < 50) {
    float m = -1e30f;
    for (int k = 0; k < 20; ++k) m = fmaxf(m, r[tid * 128 + 1 + k]);
    float s = 0.f;
    for (int k = 0; k < 20; ++k) s += expf(r[tid * 128 + 1 + k] - m);
    mx[tid] = m;
    dn[tid] = 1.f / s;
  }
  __syncthreads();
  for (int idx = tid; idx < 50; idx += 256)
    out[O_EOS + (size_t)b * Tn + t0 + idx] = r[idx * 128];
  for (int idx = tid; idx < 50 * 20; idx += 256) {
    const int tt = idx / 20, k = idx % 20;
    const size_t o = ((size_t)b * Tn + t0 + tt) * 20 + k;
    const float* rr = &r[tt * 128];
    out[O_PI + o] = expf(rr[1 + k] - mx[tt]) * dn[tt];
    out[O_MUX + o] = rr[21 + k];
    out[O_MUY + o] = rr[41 + k];
    out[O_SX + o] = expf(rr[61 + k]) + 1e-6f;
    out[O_SY + o] = expf(rr[81 + k]) + 1e-6f;
    out[O_RHO + o] = tanhf(rr[101 + k]) * 0.999f;
  }
}

extern "C" void kernel_launch(void* const* d_in, const int* in_sizes, int n_in,
                              void* d_out, int out_size, void* d_ws, size_t ws_size,
                              hipStream_t stream) {
  const float* x = (const float*)d_in[0];
  const int* tok = (const int*)d_in[1];
  const float* emb = (const float*)d_in[2];
  const float* Wih1 = (const float*)d_in[3];
  const float* Whh1 = (const float*)d_in[4];
  const float* bih1 = (const float*)d_in[5];
  const float* bhh1 = (const float*)d_in[6];
  const float* Wih2 = (const float*)d_in[7];
  const float* Whh2 = (const float*)d_in[8];
  const float* bih2 = (const float*)d_in[9];
  const float* bhh2 = (const float*)d_in[10];
  const float* Wih3 = (const float*)d_in[11];
  const float* Whh3 = (const float*)d_in[12];
  const float* bih3 = (const float*)d_in[13];
  const float* bhh3 = (const float*)d_in[14];
  const float* Ww = (const float*)d_in[15];
  const float* bw = (const float*)d_in[16];
  const float* Wm = (const float*)d_in[17];
  const float* bm = (const float*)d_in[18];
  char* ws = (char*)d_ws;
  float* out = (float*)d_out;

  hipLaunchKernelGGL(init_build, dim3(1889), dim3(256), 0, stream,
                     ws, tok, emb, Wih1, Whh1, bih1, bhh1, Wih2, Whh2, bih2, bhh2,
                     Wih3, Whh3, bih3, bhh3, bw, Wm, bm);
  hipLaunchKernelGGL(init_x0, dim3(1), dim3(256), 0, stream, ws, x);

  char* ws_arg = ws;
  const float* x_arg = x;
  const float* ww_arg = Ww;
  void* kargs[] = {&ws_arg, &x_arg, &ww_arg};
  hipError_t ce = hipLaunchCooperativeKernel((const void*)coop_kernel, dim3(NWG), dim3(256),
                                             kargs, 0, stream);
  if (ce != hipSuccess) {
    // 107 WGs <= 256 CUs: co-resident under a plain launch as well
    hipLaunchKernelGGL(coop_kernel, dim3(NWG), dim3(256), 0, stream, ws, x, Ww);
  }

  hipLaunchKernelGGL(postproc, dim3(1024), dim3(256), 0, stream, ws, out);
}